// Round 11
// baseline (37641.101 us; speedup 1.0000x reference)
//
#include <hip/hip_runtime.h>
#include <cstddef>

// SafetyReflexSNN: 5-layer LIF SNN, B=128, T=512.
// Phase-pipelined across layers (layer L at phase p handles t = p - L).
//
// NUMERICS (round 11): large-Q BLAS emulation. OpenBLAS k-loop with the
// even-remainder-split rule maps EVERY SGEMM_DEFAULT_Q in [512,1023] to:
//   K=1024 -> panels (512,512) -> single fold at k=512
//   K=512  -> one panel        -> NO fold
// The same signature covers BLIS/AOCL zen4 (KC=512) and MKL-style kc=512/768
// blocking — three BLAS families, one grouping. Micro-kernel: FMA chain
// (fmaf), one accumulator per C element, ascending k, fold-left (beta=0).
// Eliminated groupings: {} (r3/r6), {256,512,768}+{256} (r8),
// {288,576,864}+{288} (r5), {320,640,832}+{256} (r9), {320,640,960}+{320}
// (r7), {384,704}+{256} (r10), {384,768}+{384} (r4), f64 (r2), fused (r1)
// — all at the 20-26 cascade-equilibrium plateau vs threshold 9.6.
//  - layer 2: two separate gemms, combined by ONE __fadd_rn
//  - LIF: __fmul_rn then __fadd_rn (numpy rounds mul and add separately)

#define NB 128
#define NT 512

enum : size_t {
  FOFF_V0  = 0,                        // [128][1024]
  FOFF_V1  = FOFF_V0 + 128 * 1024,
  FOFF_V2  = FOFF_V1 + 128 * 1024,
  FOFF_V3  = FOFF_V2 + 128 * 1024,     // [128][512]
  FOFF_VO  = FOFF_V3 + 128 * 512,      // [128][128]
  FOFF_CNT = FOFF_VO + 128 * 128,      // [128][128]
  FOFF_S0  = FOFF_CNT + 128 * 128,     // 2 x [128][1024]
  FOFF_S1  = FOFF_S0 + 2 * 128 * 1024,
  FOFF_S2  = FOFF_S1 + 2 * 128 * 1024,
  FOFF_S3  = FOFF_S2 + 2 * 128 * 1024, // 2 x [128][512]
  WS_FLOATS = FOFF_S3 + 2 * 128 * 512
};

__global__ __launch_bounds__(256) void init_kernel(float* __restrict__ wf) {
  size_t i = (size_t)blockIdx.x * blockDim.x + threadIdx.x;
  size_t stride = (size_t)gridDim.x * blockDim.x;
  for (size_t j = i; j < WS_FLOATS; j += stride) wf[j] = 0.0f;
}

// Large-Q BLAS panel boundaries: K=1024 -> fold at 512; K=512 -> none.
__device__ __forceinline__ bool is_fold(int K, int k0) {
  return (K == 1024) && (k0 == 512);
}

// 32b x 32o tile: per element, fmaf chain ascending k within panels,
// panels folded left-to-right with __fadd_rn.
__device__ __forceinline__ void gemm_blas(
    const float* __restrict__ Abase, int Astride,
    const float* __restrict__ Wbase, int K,
    int bBase, int oBase,
    float (&As)[32][33], float (&Ws)[32][33],
    float acc[2][2])
{
  const int tid = threadIdx.x;
  const int ldRow = tid >> 3;        // 0..31
  const int ldK   = (tid & 7) << 2;  // 0,4..28
  const int tb = (tid & 15) << 1;
  const int to = (tid >> 4) << 1;
  float tot[2][2]  = {{0.f, 0.f}, {0.f, 0.f}};
  float pan[2][2]  = {{0.f, 0.f}, {0.f, 0.f}};
  for (int k0 = 0; k0 < K; k0 += 32) {
    if (is_fold(K, k0)) {
      // kc-panel boundary: fold partial into C, restart chain
#pragma unroll
      for (int i = 0; i < 2; ++i)
#pragma unroll
        for (int j = 0; j < 2; ++j) {
          tot[i][j] = __fadd_rn(tot[i][j], pan[i][j]);
          pan[i][j] = 0.f;
        }
    }
    float4 av = *(const float4*)(Abase + (size_t)(bBase + ldRow) * Astride + k0 + ldK);
    float4 wv = *(const float4*)(Wbase + (size_t)(oBase + ldRow) * K       + k0 + ldK);
    As[ldK + 0][ldRow] = av.x; As[ldK + 1][ldRow] = av.y;
    As[ldK + 2][ldRow] = av.z; As[ldK + 3][ldRow] = av.w;
    Ws[ldK + 0][ldRow] = wv.x; Ws[ldK + 1][ldRow] = wv.y;
    Ws[ldK + 2][ldRow] = wv.z; Ws[ldK + 3][ldRow] = wv.w;
    __syncthreads();
#pragma unroll
    for (int k = 0; k < 32; ++k) {
      float a0 = As[k][tb], a1 = As[k][tb + 1];
      float w0 = Ws[k][to], w1 = Ws[k][to + 1];
      // FMA micro-kernel: one accumulator per element, ascending k
      pan[0][0] = fmaf(a0, w0, pan[0][0]);
      pan[0][1] = fmaf(a0, w1, pan[0][1]);
      pan[1][0] = fmaf(a1, w0, pan[1][0]);
      pan[1][1] = fmaf(a1, w1, pan[1][1]);
    }
    __syncthreads();
  }
#pragma unroll
  for (int i = 0; i < 2; ++i)
#pragma unroll
    for (int j = 0; j < 2; ++j)
      acc[i][j] = __fadd_rn(tot[i][j], pan[i][j]);  // fold last panel
}

// Blocks: L0 [0,128) L1 [128,256) L2 [256,384) L3 [384,448) L4 [448,464)
__global__ __launch_bounds__(256) void phase_kernel(
    const float* __restrict__ x,
    const float* __restrict__ W0, const float* __restrict__ W1,
    const float* __restrict__ W2a, const float* __restrict__ W2b,
    const float* __restrict__ W3, const float* __restrict__ W4,
    float* __restrict__ wf, float* __restrict__ out, int p)
{
  float* counts = wf + FOFF_CNT;
  float* s0 = wf + FOFF_S0;  float* s1 = wf + FOFF_S1;
  float* s2 = wf + FOFF_S2;  float* s3 = wf + FOFF_S3;
  const int cur = p & 1, prev = cur ^ 1;

  const int blk = blockIdx.x;
  int layer, lb, K, N, t;
  if (blk < 128)      { layer = 0; lb = blk;       t = p;     K = 512;  N = 1024; }
  else if (blk < 256) { layer = 1; lb = blk - 128; t = p - 1; K = 1024; N = 1024; }
  else if (blk < 384) { layer = 2; lb = blk - 256; t = p - 2; K = 1024; N = 1024; }
  else if (blk < 448) { layer = 3; lb = blk - 384; t = p - 3; K = 1024; N = 512;  }
  else                { layer = 4; lb = blk - 448; t = p - 4; K = 512;  N = 128;  }
  if (t < 0 || t >= NT) return;

  const int ntO = N >> 5;
  const int bBase = (lb / ntO) << 5;
  const int oBase = (lb % ntO) << 5;

  const float* A; int Astride;
  const float* Wm; float* v; float* sOut = nullptr;
  float alpha, vth;
  switch (layer) {
    case 0: A = x + (size_t)t * 512; Astride = NT * 512; Wm = W0; v = wf + FOFF_V0;
            alpha = 0.9f;  vth = 0.5f; sOut = s0 + (size_t)cur * 128 * 1024; break;
    case 1: A = s0 + (size_t)prev * 128 * 1024; Astride = 1024; Wm = W1; v = wf + FOFF_V1;
            alpha = 0.95f; vth = 0.5f; sOut = s1 + (size_t)cur * 128 * 1024; break;
    case 2: A = s1 + (size_t)prev * 128 * 1024; Astride = 1024; Wm = W2a; v = wf + FOFF_V2;
            alpha = 0.93f; vth = 0.5f; sOut = s2 + (size_t)cur * 128 * 1024; break;
    case 3: A = s2 + (size_t)prev * 128 * 1024; Astride = 1024; Wm = W3; v = wf + FOFF_V3;
            alpha = 0.9f;  vth = 0.5f; sOut = s3 + (size_t)cur * 128 * 512; break;
    default: A = s3 + (size_t)prev * 128 * 512; Astride = 512; Wm = W4; v = wf + FOFF_VO;
            alpha = 0.82f; vth = 0.8f; break;
  }

  __shared__ float As[32][33];
  __shared__ float Ws[32][33];
  float acc[2][2];

  gemm_blas(A, Astride, Wm, K, bBase, oBase, As, Ws, acc);

  float acc2[2][2];
  if (layer == 2) {
    // separate matmul (own panels); reference adds the two results once
    gemm_blas(s2 + (size_t)prev * 128 * 1024, 1024, W2b, 1024, bBase, oBase, As, Ws, acc2);
  }

  const int tid = threadIdx.x;
  const int tb = (tid & 15) << 1;
  const int to = (tid >> 4) << 1;
#pragma unroll
  for (int i = 0; i < 2; ++i) {
#pragma unroll
    for (int j = 0; j < 2; ++j) {
      const int b = bBase + tb + i;
      const int o = oBase + to + j;
      float cur_in = acc[i][j];
      if (layer == 2) cur_in = __fadd_rn(acc[i][j], acc2[i][j]);
      float* vp = v + (size_t)b * N + o;
      // numpy: mul rounded, then add rounded — NO fma
      float vv = __fadd_rn(__fmul_rn(alpha, *vp), cur_in);
      float s = (vv >= vth) ? 1.0f : 0.0f;
      *vp = __fmul_rn(vv, __fsub_rn(1.0f, s));
      if (layer < 4) {
        sOut[(size_t)b * N + o] = s;
      } else {
        out[(size_t)b * (NT * 128) + (size_t)t * 128 + o] = s;
        counts[b * 128 + o] = __fadd_rn(counts[b * 128 + o], s);  // integer-exact
      }
    }
  }
}

__global__ __launch_bounds__(256) void fin_kernel(const float* __restrict__ counts,
                                                  float* __restrict__ out) {
  int i = blockIdx.x * blockDim.x + threadIdx.x;
  if (i < 128 * 128) out[(size_t)128 * NT * 128 + i] = counts[i];
}

extern "C" void kernel_launch(void* const* d_in, const int* in_sizes, int n_in,
                              void* d_out, int out_size, void* d_ws, size_t ws_size,
                              hipStream_t stream) {
  const float* x   = (const float*)d_in[0];
  const float* W0  = (const float*)d_in[1];
  const float* W1  = (const float*)d_in[2];
  const float* W2a = (const float*)d_in[3];
  const float* W2b = (const float*)d_in[4];
  const float* W3  = (const float*)d_in[5];
  const float* W4  = (const float*)d_in[6];
  float* wf  = (float*)d_ws;
  float* out = (float*)d_out;

  init_kernel<<<256, 256, 0, stream>>>(wf);
  for (int p = 0; p < NT + 4; ++p) {
    phase_kernel<<<464, 256, 0, stream>>>(x, W0, W1, W2a, W2b, W3, W4, wf, out, p);
  }
  fin_kernel<<<64, 256, 0, stream>>>(wf + FOFF_CNT, out);
}